// Round 6
// baseline (299.600 us; speedup 1.0000x reference)
//
#include <hip/hip_runtime.h>
#include <cstdint>
#include <cstddef>

#define TOKENS 8192
#define IN_F   4096
#define OUT_F  4096
#define QMAXF  127.0f
#define EPSF   1e-8f

typedef int i32x4  __attribute__((ext_vector_type(4)));
typedef int i32x16 __attribute__((ext_vector_type(16)));

#define BKB 64                     // K-bytes per K-step
#define NT  (IN_F / BKB)           // 64 K-steps
// wave-private LDS: per wave 2 buffers x (A 8KB + B 8KB) = 32 KB; 4 waves = 128 KB
#define WAVE_LDS  32768
#define BUF_LDS   16384
#define LDS_TOTAL 131072

__device__ __forceinline__ void gload16(const void* g, void* l) {
    __builtin_amdgcn_global_load_lds(
        (const __attribute__((address_space(1))) void*)g,
        (__attribute__((address_space(3))) void*)l,
        16, 0, 0);
}

__device__ __forceinline__ int quant1(float v, float inv) {
    int q = (int)rintf(v * inv);
    q = q > 127 ? 127 : q;
    q = q < -127 ? -127 : q;
    return q;
}

__device__ __forceinline__ unsigned int pack4i(int a, int b, int c, int d) {
    return (unsigned int)(a & 255) | ((unsigned int)(b & 255) << 8) |
           ((unsigned int)(c & 255) << 16) | ((unsigned int)(d & 255) << 24);
}

// One block per token: absmax reduce + int8 quantize.
__global__ __launch_bounds__(256) void quant_x_kernel(const float* __restrict__ x,
                                                      signed char* __restrict__ xq,
                                                      float* __restrict__ xscale) {
    const int t   = blockIdx.x;
    const int tid = threadIdx.x;
    const float* xr = x + (size_t)t * IN_F + tid * 16;

    float4 v[4];
    float am = 0.0f;
#pragma unroll
    for (int i = 0; i < 4; ++i) {
        v[i] = ((const float4*)xr)[i];
        am = fmaxf(am, fmaxf(fmaxf(fabsf(v[i].x), fabsf(v[i].y)),
                             fmaxf(fabsf(v[i].z), fabsf(v[i].w))));
    }
#pragma unroll
    for (int off = 32; off >= 1; off >>= 1)
        am = fmaxf(am, __shfl_xor(am, off));

    __shared__ float wmax[4];
    const int wid = tid >> 6, lane = tid & 63;
    if (lane == 0) wmax[wid] = am;
    __syncthreads();
    am = fmaxf(fmaxf(wmax[0], wmax[1]), fmaxf(wmax[2], wmax[3]));

    const float s   = fmaxf(am, EPSF) / QMAXF;
    const float inv = QMAXF / fmaxf(am, EPSF);
    if (tid == 0) xscale[t] = s;

    unsigned int w[4];
#pragma unroll
    for (int i = 0; i < 4; ++i) {
        w[i] = pack4i(quant1(v[i].x, inv), quant1(v[i].y, inv),
                      quant1(v[i].z, inv), quant1(v[i].w, inv));
    }
    *(uint4*)(xq + (size_t)t * IN_F + tid * 16) = make_uint4(w[0], w[1], w[2], w[3]);
}

// Repack int32-held int8 weights into dense int8.
__global__ __launch_bounds__(256) void pack_w_kernel(const int* __restrict__ w,
                                                     signed char* __restrict__ wq) {
    const size_t idx = (size_t)blockIdx.x * 256 + threadIdx.x;
    const int4* src = (const int4*)w + idx * 4;
    unsigned int o[4];
#pragma unroll
    for (int i = 0; i < 4; ++i) {
        int4 u = src[i];
        o[i] = pack4i(u.x, u.y, u.z, u.w);
    }
    ((uint4*)wq)[idx] = make_uint4(o[0], o[1], o[2], o[3]);
}

// Barrier-free wave-private GEMM.
// Block 256x256, 4 waves (2x2), wave tile 128x128, mfma_i32_32x32x32_i8.
// Each wave stages its OWN A(128x64B)+B(128x64B) into wave-private LDS
// (double-buffered) via global_load_lds; NO __syncthreads in the K-loop.
// Per K-step: vmcnt(0) [own DMA from previous step, ~1500cy old] ->
// issue next step's 16 DMAs -> ds_read 16 frags -> 32 MFMA.
// LDS window layout (16 rows x 64B = 1024B): slot = granule*256 + (row&15)*16
// -> b128 fragment reads are 4x 256B-contiguous chunks (0 bank conflicts,
// verified R3-R5).
__global__ __launch_bounds__(256, 1) void gemm_kernel(const signed char* __restrict__ xq,
                                                      const signed char* __restrict__ wq,
                                                      const float* __restrict__ xscale,
                                                      const float* __restrict__ wscale,
                                                      const float* __restrict__ bias,
                                                      float* __restrict__ out) {
    extern __shared__ __align__(16) char lds[];

    const int tid  = threadIdx.x;
    const int wid  = tid >> 6;
    const int lane = tid & 63;
    const int wr   = wid >> 1;   // 0..1
    const int wc   = wid & 1;    // 0..1

    // XCD-aware bijective swizzle (512 blocks, 512 % 8 == 0)
    const int bid = blockIdx.x;
    const int swz = (bid & 7) * 64 + (bid >> 3);
    const int bm0 = (swz >> 4) * 256;   // 32 m-tiles
    const int bn0 = (swz & 15) * 256;   // 16 n-tiles

    char* wbase = lds + wid * WAVE_LDS;

    // ---- wave-private staging map ----
    // gload c covers 16 rows x 64B: lane l -> row = c*16 + (l&15), granule = l>>4
    const int l15 = lane & 15, lg = lane >> 4;
    const signed char* pA = xq + (size_t)(bm0 + wr * 128 + l15) * IN_F + lg * 16;
    const signed char* pB = wq + (size_t)(bn0 + wc * 128 + l15) * IN_F + lg * 16;
    const int dst = lane * 16;

    // ---- fragment read offsets (within wave buffer) ----
    const int l31 = lane & 31, hi = lane >> 5;
    int a_off[4][2], b_off[4][2];
#pragma unroll
    for (int m = 0; m < 4; ++m) {
        const int win = m * 2 + (l31 >> 4);
#pragma unroll
        for (int ks = 0; ks < 2; ++ks)
            a_off[m][ks] = win * 1024 + (ks * 2 + hi) * 256 + (l31 & 15) * 16;
    }
#pragma unroll
    for (int n = 0; n < 4; ++n) {
        const int win = n * 2 + (l31 >> 4);
#pragma unroll
        for (int ks = 0; ks < 2; ++ks)
            b_off[n][ks] = 8192 + win * 1024 + (ks * 2 + hi) * 256 + (l31 & 15) * 16;
    }

    i32x16 acc[4][4];
#pragma unroll
    for (int m = 0; m < 4; ++m)
#pragma unroll
        for (int n = 0; n < 4; ++n)
#pragma unroll
            for (int r = 0; r < 16; ++r) acc[m][n][r] = 0;

    // ---- prologue: stage K-step 0 into buf 0 (wave-private, no barrier) ----
#pragma unroll
    for (int c = 0; c < 8; ++c)
        gload16(pA + (size_t)c * 16 * IN_F, wbase + c * 1024 + dst);
#pragma unroll
    for (int c = 0; c < 8; ++c)
        gload16(pB + (size_t)c * 16 * IN_F, wbase + 8192 + c * 1024 + dst);

    for (int k = 0; k < NT; ++k) {
        // own staging(k) was issued one K-step ago -> wait, then refill.
        asm volatile("s_waitcnt vmcnt(0)" ::: "memory");
        __builtin_amdgcn_sched_barrier(0);

        const char* buf = wbase + (k & 1) * BUF_LDS;

        if (k + 1 < NT) {
            char* nb = wbase + ((k + 1) & 1) * BUF_LDS;
            const int ko = (k + 1) * BKB;
#pragma unroll
            for (int c = 0; c < 8; ++c)
                gload16(pA + (size_t)c * 16 * IN_F + ko, nb + c * 1024 + dst);
#pragma unroll
            for (int c = 0; c < 8; ++c)
                gload16(pB + (size_t)c * 16 * IN_F + ko, nb + 8192 + c * 1024 + dst);
        }

        // fragment reads: ks0 group first so its MFMAs can start while ks1 drains
        i32x4 a[4][2], b[4][2];
#pragma unroll
        for (int m = 0; m < 4; ++m) a[m][0] = *(const i32x4*)(buf + a_off[m][0]);
#pragma unroll
        for (int n = 0; n < 4; ++n) b[n][0] = *(const i32x4*)(buf + b_off[n][0]);
#pragma unroll
        for (int m = 0; m < 4; ++m) a[m][1] = *(const i32x4*)(buf + a_off[m][1]);
#pragma unroll
        for (int n = 0; n < 4; ++n) b[n][1] = *(const i32x4*)(buf + b_off[n][1]);

#pragma unroll
        for (int ks = 0; ks < 2; ++ks)
#pragma unroll
            for (int m = 0; m < 4; ++m)
#pragma unroll
                for (int n = 0; n < 4; ++n)
                    acc[m][n] = __builtin_amdgcn_mfma_i32_32x32x32_i8(a[m][ks], b[n][ks], acc[m][n], 0, 0, 0);
    }

    // ---- epilogue: dequant + bias ----
    // C/D 32x32 layout: col = lane&31, row = (reg&3) + 8*(reg>>2) + 4*(lane>>5)
#pragma unroll
    for (int m = 0; m < 4; ++m) {
        const int rbase = bm0 + wr * 128 + m * 32 + 4 * hi;
        float xsv[16];
#pragma unroll
        for (int r = 0; r < 16; ++r)
            xsv[r] = xscale[rbase + (r & 3) + 8 * (r >> 2)];
#pragma unroll
        for (int n = 0; n < 4; ++n) {
            const int col = bn0 + wc * 128 + n * 32 + l31;
            const float wsc = wscale[col];
            const float bv  = bias[col];
#pragma unroll
            for (int r = 0; r < 16; ++r) {
                const int row = rbase + (r & 3) + 8 * (r >> 2);
                out[(size_t)row * OUT_F + col] = (float)acc[m][n][r] * xsv[r] * wsc + bv;
            }
        }
    }
}

extern "C" void kernel_launch(void* const* d_in, const int* in_sizes, int n_in,
                              void* d_out, int out_size, void* d_ws, size_t ws_size,
                              hipStream_t stream) {
    const float* x      = (const float*)d_in[0];
    const int*   w      = (const int*)d_in[1];     // int8 weights held as int32
    const float* wscale = (const float*)d_in[2];
    const float* bias   = (const float*)d_in[3];
    float* out = (float*)d_out;

    char* ws = (char*)d_ws;
    signed char* xq  = (signed char*)ws;                                   // 33.5 MB
    signed char* wq8 = (signed char*)(ws + (size_t)TOKENS * IN_F);         // 16.8 MB
    float* xscale    = (float*)(ws + (size_t)TOKENS * IN_F + (size_t)OUT_F * IN_F);

    hipFuncSetAttribute((const void*)gemm_kernel,
                        hipFuncAttributeMaxDynamicSharedMemorySize, LDS_TOTAL);

    quant_x_kernel<<<TOKENS, 256, 0, stream>>>(x, xq, xscale);
    pack_w_kernel<<<(OUT_F * (IN_F / 16)) / 256, 256, 0, stream>>>(w, wq8);
    gemm_kernel<<<(TOKENS / 256) * (OUT_F / 256), 256, LDS_TOTAL, stream>>>(
        xq, wq8, xscale, wscale, bias, out);
}

// Round 7
// 215.104 us; speedup vs baseline: 1.3928x; 1.3928x over previous
//
#include <hip/hip_runtime.h>
#include <cstdint>
#include <cstddef>

#define TOKENS 8192
#define IN_F   4096
#define OUT_F  4096
#define QMAXF  127.0f
#define EPSF   1e-8f

typedef int i32x4  __attribute__((ext_vector_type(4)));
typedef int i32x16 __attribute__((ext_vector_type(16)));

#define BKB 128                    // K-bytes per K-tile
#define NTT (IN_F / BKB)           // 32 K-tiles
#define SLOT 65536                 // A 32 KB + B 32 KB
#define LDS_TOTAL (2 * SLOT)       // 131072

__device__ __forceinline__ void gload16(const void* g, void* l) {
    __builtin_amdgcn_global_load_lds(
        (const __attribute__((address_space(1))) void*)g,
        (__attribute__((address_space(3))) void*)l,
        16, 0, 0);
}

__device__ __forceinline__ void bar() {
    asm volatile("" ::: "memory");
    __builtin_amdgcn_s_barrier();
    asm volatile("" ::: "memory");
}

__device__ __forceinline__ int quant1(float v, float inv) {
    int q = (int)rintf(v * inv);
    q = q > 127 ? 127 : q;
    q = q < -127 ? -127 : q;
    return q;
}

__device__ __forceinline__ unsigned int pack4i(int a, int b, int c, int d) {
    return (unsigned int)(a & 255) | ((unsigned int)(b & 255) << 8) |
           ((unsigned int)(c & 255) << 16) | ((unsigned int)(d & 255) << 24);
}

// One block per token: absmax reduce + int8 quantize.
__global__ __launch_bounds__(256) void quant_x_kernel(const float* __restrict__ x,
                                                      signed char* __restrict__ xq,
                                                      float* __restrict__ xscale) {
    const int t   = blockIdx.x;
    const int tid = threadIdx.x;
    const float* xr = x + (size_t)t * IN_F + tid * 16;

    float4 v[4];
    float am = 0.0f;
#pragma unroll
    for (int i = 0; i < 4; ++i) {
        v[i] = ((const float4*)xr)[i];
        am = fmaxf(am, fmaxf(fmaxf(fabsf(v[i].x), fabsf(v[i].y)),
                             fmaxf(fabsf(v[i].z), fabsf(v[i].w))));
    }
#pragma unroll
    for (int off = 32; off >= 1; off >>= 1)
        am = fmaxf(am, __shfl_xor(am, off));

    __shared__ float wmax[4];
    const int wid = tid >> 6, lane = tid & 63;
    if (lane == 0) wmax[wid] = am;
    __syncthreads();
    am = fmaxf(fmaxf(wmax[0], wmax[1]), fmaxf(wmax[2], wmax[3]));

    const float s   = fmaxf(am, EPSF) / QMAXF;
    const float inv = QMAXF / fmaxf(am, EPSF);
    if (tid == 0) xscale[t] = s;

    unsigned int w[4];
#pragma unroll
    for (int i = 0; i < 4; ++i) {
        w[i] = pack4i(quant1(v[i].x, inv), quant1(v[i].y, inv),
                      quant1(v[i].z, inv), quant1(v[i].w, inv));
    }
    *(uint4*)(xq + (size_t)t * IN_F + tid * 16) = make_uint4(w[0], w[1], w[2], w[3]);
}

// Repack int32-held int8 weights into dense int8.
__global__ __launch_bounds__(256) void pack_w_kernel(const int* __restrict__ w,
                                                     signed char* __restrict__ wq) {
    const size_t idx = (size_t)blockIdx.x * 256 + threadIdx.x;
    const int4* src = (const int4*)w + idx * 4;
    unsigned int o[4];
#pragma unroll
    for (int i = 0; i < 4; ++i) {
        int4 u = src[i];
        o[i] = pack4i(u.x, u.y, u.z, u.w);
    }
    ((uint4*)wq)[idx] = make_uint4(o[0], o[1], o[2], o[3]);
}

// "Fat-phase" GEMM: 256x256 tile, 8 waves (2Mx4N), wave tile 128x64,
// mfma_i32_32x32x32_i8, BK=128B per K-tile (32 MFMA/wave/phase).
// 2 LDS slots (64 KB each); stage tile t+1 at phase START (8 gloads);
// ONE vmcnt(0)+barrier per K-tile at the END (issue->wait gap = full
// tile compute > HBM latency). K-tile computed in 2 register sub-phases
// (no barrier between) to cap live VGPRs.
// LDS layout: addr(r,kb) = (r>>4)*2048 + (kb>>6)*1024 + ((kb>>4)&3)*256
//             + (r&15)*16 + (kb&15)   -> b128 fragment reads are 4x
// contiguous 256B chunks: 0 bank conflicts (verified R3-R6).
__global__ __launch_bounds__(512, 2) void gemm_kernel(const signed char* __restrict__ xq,
                                                      const signed char* __restrict__ wq,
                                                      const float* __restrict__ xscale,
                                                      const float* __restrict__ wscale,
                                                      const float* __restrict__ bias,
                                                      float* __restrict__ out) {
    extern __shared__ __align__(16) char lds[];

    const int tid  = threadIdx.x;
    const int wid  = tid >> 6;
    const int lane = tid & 63;
    const int wr   = wid >> 2;   // 0..1
    const int wc   = wid & 3;    // 0..3

    // XCD-aware bijective swizzle (512 blocks, 512 % 8 == 0)
    const int bid = blockIdx.x;
    const int swz = (bid & 7) * 64 + (bid >> 3);
    const int bm0 = (swz >> 4) * 256;   // 32 m-tiles
    const int bn0 = (swz & 15) * 256;   // 16 n-tiles

    // ---- staging map (derived from LDS layout, lane-linear dest) ----
    // call c covers LDS [c*8192, +8192): row = c*64 + (tid>>7)*16 + (tid&15),
    // kb = ((tid>>6)&1)*64 + ((tid>>4)&3)*16
    const int srow = ((tid >> 7) << 4) + (tid & 15);
    const int skb  = ((tid >> 6) & 1) * 64 + (((tid >> 4) & 3) << 4);
    const signed char* pA = xq + (size_t)(bm0 + srow) * IN_F + skb;
    const signed char* pB = wq + (size_t)(bn0 + srow) * IN_F + skb;
    const int ldst = tid * 16;

    // ---- fragment read offsets ----
    const int l31 = lane & 31, hi = lane >> 5;
    int a_off[4][4], b_off[2][4];
#pragma unroll
    for (int mi = 0; mi < 4; ++mi) {
        const int row = wr * 128 + mi * 32 + l31;
#pragma unroll
        for (int ks = 0; ks < 4; ++ks)
            a_off[mi][ks] = (row >> 4) * 2048 + (ks >> 1) * 1024 +
                            (((ks & 1) * 2 + hi) << 8) + (row & 15) * 16;
    }
#pragma unroll
    for (int ni = 0; ni < 2; ++ni) {
        const int row = wc * 64 + ni * 32 + l31;
#pragma unroll
        for (int ks = 0; ks < 4; ++ks)
            b_off[ni][ks] = 32768 + (row >> 4) * 2048 + (ks >> 1) * 1024 +
                            (((ks & 1) * 2 + hi) << 8) + (row & 15) * 16;
    }

    i32x16 acc[4][2];
#pragma unroll
    for (int mi = 0; mi < 4; ++mi)
#pragma unroll
        for (int ni = 0; ni < 2; ++ni)
#pragma unroll
            for (int r = 0; r < 16; ++r) acc[mi][ni][r] = 0;

    // ---- prologue: stage tile 0 -> slot 0 ----
#pragma unroll
    for (int c = 0; c < 4; ++c)
        gload16(pA + (size_t)c * 64 * IN_F, lds + c * 8192 + ldst);
#pragma unroll
    for (int c = 0; c < 4; ++c)
        gload16(pB + (size_t)c * 64 * IN_F, lds + 32768 + c * 8192 + ldst);
    asm volatile("s_waitcnt vmcnt(0)" ::: "memory");
    bar();

    for (int t = 0; t < NTT; ++t) {
        const char* S = lds + (t & 1) * SLOT;

        // ---- issue next tile's staging FIRST (gap to vmcnt = full tile) ----
        if (t + 1 < NTT) {
            char* D = lds + ((t + 1) & 1) * SLOT;
            const int ko = (t + 1) * BKB;
#pragma unroll
            for (int c = 0; c < 4; ++c)
                gload16(pA + (size_t)c * 64 * IN_F + ko, D + c * 8192 + ldst);
#pragma unroll
            for (int c = 0; c < 4; ++c)
                gload16(pB + (size_t)c * 64 * IN_F + ko, D + 32768 + c * 8192 + ldst);
        }

        // ---- two register sub-phases, no barrier between ----
#pragma unroll
        for (int kh = 0; kh < 2; ++kh) {
            i32x4 a[4][2], b[2][2];
#pragma unroll
            for (int mi = 0; mi < 4; ++mi)
#pragma unroll
                for (int k2 = 0; k2 < 2; ++k2)
                    a[mi][k2] = *(const i32x4*)(S + a_off[mi][kh * 2 + k2]);
#pragma unroll
            for (int ni = 0; ni < 2; ++ni)
#pragma unroll
                for (int k2 = 0; k2 < 2; ++k2)
                    b[ni][k2] = *(const i32x4*)(S + b_off[ni][kh * 2 + k2]);

            __builtin_amdgcn_s_setprio(1);
#pragma unroll
            for (int k2 = 0; k2 < 2; ++k2)
#pragma unroll
                for (int mi = 0; mi < 4; ++mi)
#pragma unroll
                    for (int ni = 0; ni < 2; ++ni)
                        acc[mi][ni] = __builtin_amdgcn_mfma_i32_32x32x32_i8(
                            a[mi][k2], b[ni][k2], acc[mi][ni], 0, 0, 0);
            __builtin_amdgcn_s_setprio(0);
        }

        // ---- tile boundary: next tile's staging must have landed ----
        asm volatile("s_waitcnt vmcnt(0)" ::: "memory");
        bar();
    }

    // ---- epilogue: dequant + bias ----
    // C/D 32x32 layout: col = lane&31, row = (reg&3) + 8*(reg>>2) + 4*(lane>>5)
#pragma unroll
    for (int mi = 0; mi < 4; ++mi) {
        const int rbase = bm0 + wr * 128 + mi * 32 + 4 * hi;
        float xsv[16];
#pragma unroll
        for (int r = 0; r < 16; ++r)
            xsv[r] = xscale[rbase + (r & 3) + 8 * (r >> 2)];
#pragma unroll
        for (int ni = 0; ni < 2; ++ni) {
            const int col = bn0 + wc * 64 + ni * 32 + l31;
            const float wsc = wscale[col];
            const float bv  = bias[col];
#pragma unroll
            for (int r = 0; r < 16; ++r) {
                const int row = rbase + (r & 3) + 8 * (r >> 2);
                out[(size_t)row * OUT_F + col] = (float)acc[mi][ni][r] * xsv[r] * wsc + bv;
            }
        }
    }
}

extern "C" void kernel_launch(void* const* d_in, const int* in_sizes, int n_in,
                              void* d_out, int out_size, void* d_ws, size_t ws_size,
                              hipStream_t stream) {
    const float* x      = (const float*)d_in[0];
    const int*   w      = (const int*)d_in[1];     // int8 weights held as int32
    const float* wscale = (const float*)d_in[2];
    const float* bias   = (const float*)d_in[3];
    float* out = (float*)d_out;

    char* ws = (char*)d_ws;
    signed char* xq  = (signed char*)ws;                                   // 33.5 MB
    signed char* wq8 = (signed char*)(ws + (size_t)TOKENS * IN_F);         // 16.8 MB
    float* xscale    = (float*)(ws + (size_t)TOKENS * IN_F + (size_t)OUT_F * IN_F);

    hipFuncSetAttribute((const void*)gemm_kernel,
                        hipFuncAttributeMaxDynamicSharedMemorySize, LDS_TOTAL);

    quant_x_kernel<<<TOKENS, 256, 0, stream>>>(x, xq, xscale);
    pack_w_kernel<<<(OUT_F * (IN_F / 16)) / 256, 256, 0, stream>>>(w, wq8);
    gemm_kernel<<<(TOKENS / 256) * (OUT_F / 256), 512, LDS_TOTAL, stream>>>(
        xq, wq8, xscale, wscale, bias, out);
}

// Round 8
// 199.674 us; speedup vs baseline: 1.5004x; 1.0773x over previous
//
#include <hip/hip_runtime.h>
#include <cstdint>
#include <cstddef>

#define TOKENS 8192
#define IN_F   4096
#define OUT_F  4096
#define QMAXF  127.0f
#define EPSF   1e-8f

typedef int i32x4 __attribute__((ext_vector_type(4)));

#define NIT   32                  // iterations; each covers 2 K-halves of 64 B
#define SLOTB 32768               // half-slot: A 16 KB + B 16 KB
#define LDS_TOTAL (4 * SLOTB)     // 131072

__device__ __forceinline__ void gload16(const void* g, void* l) {
    __builtin_amdgcn_global_load_lds(
        (const __attribute__((address_space(1))) void*)g,
        (__attribute__((address_space(3))) void*)l,
        16, 0, 0);
}

__device__ __forceinline__ void bar() {
    asm volatile("" ::: "memory");
    __builtin_amdgcn_s_barrier();
    asm volatile("" ::: "memory");
}

// rule #18: inline-asm lgkmcnt(0) needs a following sched_barrier(0)
__device__ __forceinline__ void lgkm0_fence() {
    asm volatile("s_waitcnt lgkmcnt(0)" ::: "memory");
    __builtin_amdgcn_sched_barrier(0);
}

__device__ __forceinline__ int quant1(float v, float inv) {
    int q = (int)rintf(v * inv);
    q = q > 127 ? 127 : q;
    q = q < -127 ? -127 : q;
    return q;
}

__device__ __forceinline__ unsigned int pack4i(int a, int b, int c, int d) {
    return (unsigned int)(a & 255) | ((unsigned int)(b & 255) << 8) |
           ((unsigned int)(c & 255) << 16) | ((unsigned int)(d & 255) << 24);
}

// One block per token: absmax reduce + int8 quantize.
__global__ __launch_bounds__(256) void quant_x_kernel(const float* __restrict__ x,
                                                      signed char* __restrict__ xq,
                                                      float* __restrict__ xscale) {
    const int t   = blockIdx.x;
    const int tid = threadIdx.x;
    const float* xr = x + (size_t)t * IN_F + tid * 16;

    float4 v[4];
    float am = 0.0f;
#pragma unroll
    for (int i = 0; i < 4; ++i) {
        v[i] = ((const float4*)xr)[i];
        am = fmaxf(am, fmaxf(fmaxf(fabsf(v[i].x), fabsf(v[i].y)),
                             fmaxf(fabsf(v[i].z), fabsf(v[i].w))));
    }
#pragma unroll
    for (int off = 32; off >= 1; off >>= 1)
        am = fmaxf(am, __shfl_xor(am, off));

    __shared__ float wmax[4];
    const int wid = tid >> 6, lane = tid & 63;
    if (lane == 0) wmax[wid] = am;
    __syncthreads();
    am = fmaxf(fmaxf(wmax[0], wmax[1]), fmaxf(wmax[2], wmax[3]));

    const float s   = fmaxf(am, EPSF) / QMAXF;
    const float inv = QMAXF / fmaxf(am, EPSF);
    if (tid == 0) xscale[t] = s;

    unsigned int w[4];
#pragma unroll
    for (int i = 0; i < 4; ++i) {
        w[i] = pack4i(quant1(v[i].x, inv), quant1(v[i].y, inv),
                      quant1(v[i].z, inv), quant1(v[i].w, inv));
    }
    *(uint4*)(xq + (size_t)t * IN_F + tid * 16) = make_uint4(w[0], w[1], w[2], w[3]);
}

// Repack int32-held int8 weights into dense int8.
__global__ __launch_bounds__(256) void pack_w_kernel(const int* __restrict__ w,
                                                     signed char* __restrict__ wq) {
    const size_t idx = (size_t)blockIdx.x * 256 + threadIdx.x;
    const int4* src = (const int4*)w + idx * 4;
    unsigned int o[4];
#pragma unroll
    for (int i = 0; i < 4; ++i) {
        int4 u = src[i];
        o[i] = pack4i(u.x, u.y, u.z, u.w);
    }
    ((uint4*)wq)[idx] = make_uint4(o[0], o[1], o[2], o[3]);
}

// Faithful i8 port of the verified m201 8-phase 256^2 template.
// mfma_i32_16x16x64_i8 (byte-identical frag geometry to bf16 16x16x32).
// 8 waves (2Mx4N), per-wave C = 128x64 (8x4 tiles), iteration = 2 K-halves
// (64 B each) = 4 phases. Phase: {ds_read 8-or-4 b128 | 2 gload_lds ->
// barrier -> lgkmcnt(0)+sched_barrier(0) -> setprio(1) -> 16 MFMA ->
// setprio(0) -> [vmcnt(8) at half boundary] -> barrier}.
// 4 half-slots (128 KB), stage lead = 3 halves -> vmcnt(8) never blocks.
// LDS window layout (16 rows x 64 B): addr = win*1024 + (l>>4)*256 +
// (l&15)*16 -> 0 bank conflicts (verified R3-R7).
__global__ __launch_bounds__(512, 2) void gemm_kernel(const signed char* __restrict__ xq,
                                                      const signed char* __restrict__ wq,
                                                      const float* __restrict__ xscale,
                                                      const float* __restrict__ wscale,
                                                      const float* __restrict__ bias,
                                                      float* __restrict__ out) {
    extern __shared__ __align__(16) char lds[];

    const int tid  = threadIdx.x;
    const int wid  = tid >> 6;
    const int lane = tid & 63;
    const int wr   = wid >> 2;   // 0..1
    const int wc   = wid & 3;    // 0..3

    // XCD-aware bijective swizzle (512 blocks, 512 % 8 == 0)
    const int bid = blockIdx.x;
    const int swz = (bid & 7) * 64 + (bid >> 3);
    const int bm0 = (swz >> 4) * 256;   // 32 m-tiles
    const int bn0 = (swz & 15) * 256;   // 16 n-tiles

    // ---- staging map: call c covers rows [c*128, c*128+128) of the panel ----
    const int srow = ((tid >> 6) << 4) + (tid & 15);   // row within 128-row call
    const int sgrn = ((tid >> 4) & 3) << 4;            // 16B k-granule within 64B half
    const signed char* pA = xq + (size_t)(bm0 + srow) * IN_F + sgrn;
    const signed char* pB = wq + (size_t)(bn0 + srow) * IN_F + sgrn;
    const int ldst = tid * 16;

    // ---- fragment read offsets (within slot) ----
    const int lrd = (lane >> 4) * 256 + (lane & 15) * 16;
    int a_off[8], b_off[4];
#pragma unroll
    for (int mi = 0; mi < 8; ++mi) a_off[mi] = (wr * 8 + mi) * 1024 + lrd;
#pragma unroll
    for (int ni = 0; ni < 4; ++ni) b_off[ni] = 16384 + (wc * 4 + ni) * 1024 + lrd;

    i32x4 acc[8][4];
#pragma unroll
    for (int mi = 0; mi < 8; ++mi)
#pragma unroll
        for (int ni = 0; ni < 4; ++ni)
#pragma unroll
            for (int r = 0; r < 4; ++r) acc[mi][ni][r] = 0;

    // ---- prologue: stage halves 0,1,2 -> slots 0,1,2 (order A,B per half) ----
#pragma unroll
    for (int s = 0; s < 3; ++s) {
        char* S = lds + s * SLOTB;
        const int ko = s * 64;
        gload16(pA + ko,                         S + ldst);
        gload16(pA + (size_t)128 * IN_F + ko,    S + 8192 + ldst);
        gload16(pB + ko,                         S + 16384 + ldst);
        gload16(pB + (size_t)128 * IN_F + ko,    S + 24576 + ldst);
    }
    asm volatile("s_waitcnt vmcnt(8)" ::: "memory");  // half 0 landed
    bar();

    for (int t = 0; t < NIT; ++t) {
        const int h0 = 2 * t;
        const char* S0 = lds + (h0 & 3) * SLOTB;
        const char* S1 = lds + ((h0 + 1) & 3) * SLOTB;
        char* G0 = lds + ((h0 + 3) & 3) * SLOTB;   // dest for half h0+3
        char* G1 = lds + ((h0 + 4) & 3) * SLOTB;   // dest for half h0+4
        const bool st0 = (h0 + 3) < 64;
        const bool st1 = (h0 + 4) < 64;
        const int ko0 = (h0 + 3) * 64;
        const int ko1 = (h0 + 4) * 64;

        i32x4 a[4], b[4];

        // ---------- phase 0: half h0, mi 0-3, all ni ----------
#pragma unroll
        for (int ni = 0; ni < 4; ++ni) b[ni] = *(const i32x4*)(S0 + b_off[ni]);
#pragma unroll
        for (int mi = 0; mi < 4; ++mi) a[mi] = *(const i32x4*)(S0 + a_off[mi]);
        if (st0) {
            gload16(pA + ko0,                      G0 + ldst);
            gload16(pA + (size_t)128 * IN_F + ko0, G0 + 8192 + ldst);
        }
        bar();
        lgkm0_fence();
        __builtin_amdgcn_s_setprio(1);
#pragma unroll
        for (int mi = 0; mi < 4; ++mi)
#pragma unroll
            for (int ni = 0; ni < 4; ++ni)
                acc[mi][ni] = __builtin_amdgcn_mfma_i32_16x16x64_i8(a[mi], b[ni], acc[mi][ni], 0, 0, 0);
        __builtin_amdgcn_s_setprio(0);
        bar();

        // ---------- phase 1: half h0, mi 4-7 (B held) ----------
#pragma unroll
        for (int mi = 0; mi < 4; ++mi) a[mi] = *(const i32x4*)(S0 + a_off[4 + mi]);
        if (st0) {
            gload16(pB + ko0,                      G0 + 16384 + ldst);
            gload16(pB + (size_t)128 * IN_F + ko0, G0 + 24576 + ldst);
        }
        bar();
        lgkm0_fence();
        __builtin_amdgcn_s_setprio(1);
#pragma unroll
        for (int mi = 0; mi < 4; ++mi)
#pragma unroll
            for (int ni = 0; ni < 4; ++ni)
                acc[4 + mi][ni] = __builtin_amdgcn_mfma_i32_16x16x64_i8(a[mi], b[ni], acc[4 + mi][ni], 0, 0, 0);
        __builtin_amdgcn_s_setprio(0);
        // half boundary: ensure half h0+1 landed (its loads are 3 halves old)
        if (t < NIT - 1) {
            asm volatile("s_waitcnt vmcnt(8)" ::: "memory");
        } else {
            asm volatile("s_waitcnt vmcnt(0)" ::: "memory");
        }
        bar();

        // ---------- phase 2: half h0+1, mi 0-3, all ni ----------
#pragma unroll
        for (int ni = 0; ni < 4; ++ni) b[ni] = *(const i32x4*)(S1 + b_off[ni]);
#pragma unroll
        for (int mi = 0; mi < 4; ++mi) a[mi] = *(const i32x4*)(S1 + a_off[mi]);
        if (st1) {
            gload16(pA + ko1,                      G1 + ldst);
            gload16(pA + (size_t)128 * IN_F + ko1, G1 + 8192 + ldst);
        }
        bar();
        lgkm0_fence();
        __builtin_amdgcn_s_setprio(1);
#pragma unroll
        for (int mi = 0; mi < 4; ++mi)
#pragma unroll
            for (int ni = 0; ni < 4; ++ni)
                acc[mi][ni] = __builtin_amdgcn_mfma_i32_16x16x64_i8(a[mi], b[ni], acc[mi][ni], 0, 0, 0);
        __builtin_amdgcn_s_setprio(0);
        bar();

        // ---------- phase 3: half h0+1, mi 4-7 (B held) ----------
#pragma unroll
        for (int mi = 0; mi < 4; ++mi) a[mi] = *(const i32x4*)(S1 + a_off[4 + mi]);
        if (st1) {
            gload16(pB + ko1,                      G1 + 16384 + ldst);
            gload16(pB + (size_t)128 * IN_F + ko1, G1 + 24576 + ldst);
        }
        bar();
        lgkm0_fence();
        __builtin_amdgcn_s_setprio(1);
#pragma unroll
        for (int mi = 0; mi < 4; ++mi)
#pragma unroll
            for (int ni = 0; ni < 4; ++ni)
                acc[4 + mi][ni] = __builtin_amdgcn_mfma_i32_16x16x64_i8(a[mi], b[ni], acc[4 + mi][ni], 0, 0, 0);
        __builtin_amdgcn_s_setprio(0);
        // half boundary: ensure half h0+2 landed before next iteration
        if (t < NIT - 2) {
            asm volatile("s_waitcnt vmcnt(8)" ::: "memory");
        } else if (t == NIT - 2) {
            asm volatile("s_waitcnt vmcnt(4)" ::: "memory");
        } else {
            asm volatile("s_waitcnt vmcnt(0)" ::: "memory");
        }
        bar();
    }

    // ---- epilogue: dequant + bias ----
    // 16x16 C/D layout: col = lane&15, row = (lane>>4)*4 + reg
    const int l15 = lane & 15, lq = lane >> 4;
#pragma unroll
    for (int mi = 0; mi < 8; ++mi) {
        const int rbase = bm0 + wr * 128 + mi * 16 + lq * 4;
        float xsv[4];
#pragma unroll
        for (int j = 0; j < 4; ++j) xsv[j] = xscale[rbase + j];
#pragma unroll
        for (int ni = 0; ni < 4; ++ni) {
            const int col = bn0 + wc * 64 + ni * 16 + l15;
            const float wsc = wscale[col];
            const float bv  = bias[col];
#pragma unroll
            for (int j = 0; j < 4; ++j) {
                out[(size_t)(rbase + j) * OUT_F + col] =
                    (float)acc[mi][ni][j] * xsv[j] * wsc + bv;
            }
        }
    }
}

extern "C" void kernel_launch(void* const* d_in, const int* in_sizes, int n_in,
                              void* d_out, int out_size, void* d_ws, size_t ws_size,
                              hipStream_t stream) {
    const float* x      = (const float*)d_in[0];
    const int*   w      = (const int*)d_in[1];     // int8 weights held as int32
    const float* wscale = (const float*)d_in[2];
    const float* bias   = (const float*)d_in[3];
    float* out = (float*)d_out;

    char* ws = (char*)d_ws;
    signed char* xq  = (signed char*)ws;                                   // 33.5 MB
    signed char* wq8 = (signed char*)(ws + (size_t)TOKENS * IN_F);         // 16.8 MB
    float* xscale    = (float*)(ws + (size_t)TOKENS * IN_F + (size_t)OUT_F * IN_F);

    hipFuncSetAttribute((const void*)gemm_kernel,
                        hipFuncAttributeMaxDynamicSharedMemorySize, LDS_TOTAL);

    quant_x_kernel<<<TOKENS, 256, 0, stream>>>(x, xq, xscale);
    pack_w_kernel<<<(OUT_F * (IN_F / 16)) / 256, 256, 0, stream>>>(w, wq8);
    gemm_kernel<<<(TOKENS / 256) * (OUT_F / 256), 512, LDS_TOTAL, stream>>>(
        xq, wq8, xscale, wscale, bias, out);
}